// Round 7
// baseline (1058.242 us; speedup 1.0000x reference)
//
#include <hip/hip_runtime.h>

typedef unsigned short u16;
typedef unsigned int   u32;

#define D_MODEL 1024
#define D_INNER 2048
#define D_STATE 16
#define SEQLEN  2048
#define BATCH   4
#define NROWS   (BATCH*SEQLEN)   // 8192
#define CHUNK   128
#define NCHUNK  (SEQLEN/CHUNK)   // 16

__device__ __forceinline__ float b2f(u16 v){
  union { u32 i; float f; } u; u.i = ((u32)v) << 16; return u.f;
}
__device__ __forceinline__ u16 f2b(float f){
  union { float f; u32 i; } u; u.f = f;
  u32 x = u.i;
  return (u16)((x + 0x7fffu + ((x >> 16) & 1u)) >> 16);  // RNE
}
__device__ __forceinline__ float h2f(u16 v){
  _Float16 h; __builtin_memcpy(&h, &v, 2); return (float)h;
}
__device__ __forceinline__ u16 f2h(float f){
  _Float16 h = (_Float16)f; u16 v; __builtin_memcpy(&v, &h, 2); return v;
}

typedef __bf16 bf16x8 __attribute__((ext_vector_type(8)));
typedef float  f32x4  __attribute__((ext_vector_type(4)));

// ---------------------------------------------------------------------------
// fp32 [Kd][Nd] -> bf16 transposed [Nd][Kd]   (32x32 LDS tiles)
// ---------------------------------------------------------------------------
__global__ __launch_bounds__(256) void wcvt_t_kernel(
    const float* __restrict__ W, u16* __restrict__ Bt, int Kd, int Nd)
{
  __shared__ u16 tile[32][33];
  const int n0 = blockIdx.x*32, k0 = blockIdx.y*32;
  const int tx = threadIdx.x & 31, ty = threadIdx.x >> 5;  // ty 0..7
  #pragma unroll
  for (int i=0;i<32;i+=8)
    tile[ty+i][tx] = f2b(W[(size_t)(k0+ty+i)*Nd + n0+tx]);   // tile[k][n]
  __syncthreads();
  #pragma unroll
  for (int i=0;i<32;i+=8)
    Bt[(size_t)(n0+ty+i)*Kd + k0+tx] = tile[tx][ty+i];
}

// Wx [2048][32] cols 16..31 -> Wxt bf16 [16][2048]
__global__ __launch_bounds__(256) void wxcvt_kernel(
    const float* __restrict__ Wx, u16* __restrict__ Wxt)
{
  const int k = blockIdx.x*256 + threadIdx.x;   // 0..2047
  #pragma unroll
  for (int n=0;n<16;n++)
    Wxt[n*D_INNER + k] = f2b(Wx[(size_t)k*32 + 16 + n]);
}

// ---------------------------------------------------------------------------
// Fused LayerNorm: x[row][1024] fp32 -> xn bf16
// ---------------------------------------------------------------------------
__global__ __launch_bounds__(256) void ln_kernel(
    const float* __restrict__ x, const float* __restrict__ g,
    const float* __restrict__ be, u16* __restrict__ xn)
{
  const int row = blockIdx.x;
  const float* xr = x + (size_t)row * D_MODEL;
  const int tid = threadIdx.x;
  float v[4]; float s = 0.f, s2 = 0.f;
  #pragma unroll
  for (int j=0;j<4;j++){
    float f = xr[tid + 256*j];
    v[j] = f; s += f; s2 += f*f;
  }
  #pragma unroll
  for (int o=32;o>0;o>>=1){ s += __shfl_down(s,o); s2 += __shfl_down(s2,o); }
  __shared__ float sh[8];
  const int wave = tid>>6, lane = tid&63;
  if (lane==0){ sh[wave]=s; sh[4+wave]=s2; }
  __syncthreads();
  const float ts  = sh[0]+sh[1]+sh[2]+sh[3];
  const float ts2 = sh[4]+sh[5]+sh[6]+sh[7];
  const float mu  = ts * (1.f/D_MODEL);
  const float var = ts2 * (1.f/D_MODEL) - mu*mu;
  const float rstd = rsqrtf(var + 1e-5f);
  u16* xo = xn + (size_t)row * D_MODEL;
  #pragma unroll
  for (int j=0;j<4;j++){
    int i = tid + 256*j;
    xo[i] = f2b((v[j]-mu)*rstd * g[i] + be[i]);
  }
}

// ---------------------------------------------------------------------------
// Direct-to-register MFMA GEMM (no LDS, no barriers; hipBLASLt-style).
// A [M][K] bf16 ; Bt [N][K] bf16 (pre-transposed weight). 128x128 block,
// 4 waves in 2x2 grid, each wave 64x64 output = 4x4 16x16x32 MFMA accs.
// Fragments are 16B-contiguous per lane in global -> global_load_dwordx4
// straight into VGPRs; K-loop unrolled x2 with two register fragment sets
// (loads for step k+1 in flight during MFMA of step k; waves self-paced).
// EPI 0: bf16 ; EPI 1: softplus(v+bias)->fp16 ; EPI 2: v+resid->fp32
// ---------------------------------------------------------------------------
template<int EPI>
__global__ __launch_bounds__(256) void gemm_direct(
    const u16* __restrict__ A, const u16* __restrict__ Bt,
    const float* __restrict__ bias, const float* __restrict__ resid,
    void* __restrict__ outv, int M, int N, int K)
{
  const int tid  = threadIdx.x;
  const int wave = tid >> 6, lane = tid & 63;
  const int quad = lane >> 4, l16 = lane & 15;
  const int m0 = blockIdx.y*128 + (wave & 1)*64;
  const int n0 = blockIdx.x*128 + (wave >> 1)*64;

  const u16* pa[4]; const u16* pb[4];
  #pragma unroll
  for (int f=0; f<4; f++){
    pa[f] = A  + (size_t)(m0 + f*16 + l16)*K + quad*8;
    pb[f] = Bt + (size_t)(n0 + f*16 + l16)*K + quad*8;
  }

  f32x4 acc[4][4];
  #pragma unroll
  for (int i=0;i<4;i++)
    #pragma unroll
    for (int j=0;j<4;j++) acc[i][j] = (f32x4){0.f,0.f,0.f,0.f};

  bf16x8 a0[4], b0[4], a1[4], b1[4];
  #pragma unroll
  for (int f=0; f<4; f++){
    a0[f] = *reinterpret_cast<const bf16x8*>(pa[f]);
    b0[f] = *reinterpret_cast<const bf16x8*>(pb[f]);
  }

  for (int k0 = 0; k0 < K; k0 += 64){
    #pragma unroll
    for (int f=0; f<4; f++){
      a1[f] = *reinterpret_cast<const bf16x8*>(pa[f] + k0 + 32);
      b1[f] = *reinterpret_cast<const bf16x8*>(pb[f] + k0 + 32);
    }
    #pragma unroll
    for (int mf=0; mf<4; mf++)
      #pragma unroll
      for (int nf=0; nf<4; nf++)
        acc[mf][nf] = __builtin_amdgcn_mfma_f32_16x16x32_bf16(a0[mf], b0[nf], acc[mf][nf], 0, 0, 0);
    if (k0 + 64 < K){
      #pragma unroll
      for (int f=0; f<4; f++){
        a0[f] = *reinterpret_cast<const bf16x8*>(pa[f] + k0 + 64);
        b0[f] = *reinterpret_cast<const bf16x8*>(pb[f] + k0 + 64);
      }
    }
    #pragma unroll
    for (int mf=0; mf<4; mf++)
      #pragma unroll
      for (int nf=0; nf<4; nf++)
        acc[mf][nf] = __builtin_amdgcn_mfma_f32_16x16x32_bf16(a1[mf], b1[nf], acc[mf][nf], 0, 0, 0);
  }

  #pragma unroll
  for (int mf=0; mf<4; mf++){
    #pragma unroll
    for (int nf=0; nf<4; nf++){
      const int col = n0 + nf*16 + l16;
      #pragma unroll
      for (int j=0;j<4;j++){
        const int row = m0 + mf*16 + quad*4 + j;
        float v = acc[mf][nf][j];
        if (EPI == 1) {
          v += bias[col];
          v = (v > 20.f) ? v : log1pf(__expf(v));
          ((u16*)outv)[(size_t)row*N + col] = f2h(v);       // delta fp16
        } else if (EPI == 2) {
          v += resid[(size_t)row*N + col];
          ((float*)outv)[(size_t)row*N + col] = v;          // final out fp32
        } else {
          ((u16*)outv)[(size_t)row*N + col] = f2b(v);       // bf16 activation
        }
      }
    }
  }
}

// ---------------------------------------------------------------------------
// Causal depthwise conv(width 4) + bias + SiLU.  u_pre = xz[:, 0:2048] (bf16).
// ---------------------------------------------------------------------------
__global__ __launch_bounds__(256) void conv_silu_kernel(
    const u16* __restrict__ xz, const float* __restrict__ cw,
    const float* __restrict__ cb, u16* __restrict__ u)
{
  const int idx = blockIdx.x*256 + threadIdx.x;  // = bt*2048 + c
  const int c  = idx & (D_INNER-1);
  const int t  = (idx >> 11) & (SEQLEN-1);
  const int bt = idx >> 11;
  float acc = cb[c];
  #pragma unroll
  for (int k=0;k<4;k++){
    int tt = t - 3 + k;
    if (tt >= 0)
      acc += cw[c*4 + k] * b2f(xz[(size_t)(bt - 3 + k)*4096 + c]);
  }
  float sv = acc / (1.f + __expf(-acc));
  u[(size_t)bt*D_INNER + c] = f2b(sv);
}

// ---------------------------------------------------------------------------
// x_proj (cols 16..31 only): one wave per row, lane=(kq,n), vectorized bf16x8
// on both streams (Wxt pre-transposed [16][2048] bf16).
// ---------------------------------------------------------------------------
__global__ __launch_bounds__(256) void xproj_kernel(
    const u16* __restrict__ u, const u16* __restrict__ Wxt, float* __restrict__ Bm)
{
  const int wave = threadIdx.x >> 6, lane = threadIdx.x & 63;
  const int m = blockIdx.x*4 + wave;
  const int n = lane & 15, kq = lane >> 4;
  const u16* ur = u   + (size_t)m*D_INNER + kq*512;
  const u16* wr = Wxt + (size_t)n*D_INNER + kq*512;
  float acc = 0.f;
  #pragma unroll 4
  for (int i=0;i<512;i+=8){
    bf16x8 uv = *reinterpret_cast<const bf16x8*>(ur + i);
    bf16x8 wv = *reinterpret_cast<const bf16x8*>(wr + i);
    #pragma unroll
    for (int j=0;j<8;j++) acc = fmaf((float)uv[j], (float)wv[j], acc);
  }
  acc += __shfl_xor(acc, 16);
  acc += __shfl_xor(acc, 32);
  if (lane < 16) Bm[(size_t)m*16 + n] = acc;
}

// ---------------------------------------------------------------------------
// Chunked selective scan, 3 passes (exact linear-recurrence decomposition).
// ---------------------------------------------------------------------------
__global__ __launch_bounds__(256) void scan_partial(
    const u16* __restrict__ uu, const u16* __restrict__ delta16,
    const float* __restrict__ Bm, const float* __restrict__ Alog,
    float* __restrict__ hend, float* __restrict__ sumdt)
{
  const int b = blockIdx.y, ch = blockIdx.z;
  const int c = blockIdx.x*256 + threadIdx.x;
  const int row0 = b*SEQLEN + ch*CHUNK;
  float A[16], h[16];
  #pragma unroll
  for (int s=0;s<16;s++){ A[s] = -__expf(Alog[c*16+s]); h[s]=0.f; }
  __shared__ float Bsh[CHUNK*16];
  const float* src = Bm + (size_t)row0*16;
  #pragma unroll
  for (int j=0;j<8;j++) Bsh[threadIdx.x + 256*j] = src[threadIdx.x + 256*j];
  __syncthreads();

  float S = 0.f;
  float dta[8], uva[8], dtb[8], uvb[8];
  #pragma unroll
  for (int j=0;j<8;j++){
    size_t r = (size_t)(row0+j);
    dta[j] = h2f(delta16[r*D_INNER+c]);
    uva[j] = b2f(uu[r*D_INNER+c]);
  }
  #pragma unroll 1
  for (int g=0; g<CHUNK; g+=16){
    #pragma unroll
    for (int j=0;j<8;j++){
      int tl = g+8+j; tl = tl < CHUNK ? tl : CHUNK-1;
      size_t r = (size_t)(row0+tl);
      dtb[j] = h2f(delta16[r*D_INNER+c]);
      uvb[j] = b2f(uu[r*D_INNER+c]);
    }
    #pragma unroll
    for (int j=0;j<8;j++){
      float dt=dta[j], uv=uva[j]; S += dt; float xv=dt*uv;
      const float* Bt = &Bsh[(g+j)*16];
      #pragma unroll
      for (int s=0;s<16;s++) h[s] = fmaf(h[s], __expf(dt*A[s]), xv*Bt[s]);
    }
    #pragma unroll
    for (int j=0;j<8;j++){
      int tl = g+16+j; tl = tl < CHUNK ? tl : CHUNK-1;
      size_t r = (size_t)(row0+tl);
      dta[j] = h2f(delta16[r*D_INNER+c]);
      uva[j] = b2f(uu[r*D_INNER+c]);
    }
    #pragma unroll
    for (int j=0;j<8;j++){
      float dt=dtb[j], uv=uvb[j]; S += dt; float xv=dt*uv;
      const float* Bt = &Bsh[(g+8+j)*16];
      #pragma unroll
      for (int s=0;s<16;s++) h[s] = fmaf(h[s], __expf(dt*A[s]), xv*Bt[s]);
    }
  }
  const size_t base = ((size_t)(b*NCHUNK+ch)*16)*D_INNER + c;
  #pragma unroll
  for (int s=0;s<16;s++) hend[base + (size_t)s*D_INNER] = h[s];
  sumdt[(size_t)(b*NCHUNK+ch)*D_INNER + c] = S;
}

__global__ __launch_bounds__(256) void scan_combine(
    const float* __restrict__ hend, const float* __restrict__ sumdt,
    const float* __restrict__ Alog, float* __restrict__ hin)
{
  const int b = blockIdx.y;
  const int c = blockIdx.x*256 + threadIdx.x;
  float A[16], h[16];
  #pragma unroll
  for (int s=0;s<16;s++){ A[s] = -__expf(Alog[c*16+s]); h[s]=0.f; }
  #pragma unroll 1
  for (int k=0;k<NCHUNK;k++){
    const size_t base = ((size_t)(b*NCHUNK+k)*16)*D_INNER + c;
    #pragma unroll
    for (int s=0;s<16;s++) hin[base + (size_t)s*D_INNER] = h[s];
    const float S = sumdt[(size_t)(b*NCHUNK+k)*D_INNER + c];
    #pragma unroll
    for (int s=0;s<16;s++)
      h[s] = fmaf(h[s], __expf(S*A[s]), hend[base + (size_t)s*D_INNER]);
  }
}

__global__ __launch_bounds__(256) void scan_final(
    const u16* __restrict__ uu, const u16* __restrict__ delta16,
    const float* __restrict__ Bm, const u16* __restrict__ xz,
    const float* __restrict__ Alog, const float* __restrict__ Dpar,
    const float* __restrict__ hin, u16* __restrict__ yg)
{
  const int b = blockIdx.y, ch = blockIdx.z;
  const int c = blockIdx.x*256 + threadIdx.x;
  const int row0 = b*SEQLEN + ch*CHUNK;
  float A[16], h[16];
  const size_t base = ((size_t)(b*NCHUNK+ch)*16)*D_INNER + c;
  #pragma unroll
  for (int s=0;s<16;s++){
    A[s] = -__expf(Alog[c*16+s]);
    h[s] = hin[base + (size_t)s*D_INNER];
  }
  const float Dc = Dpar[c];
  __shared__ float Bsh[CHUNK*16];
  const float* src = Bm + (size_t)row0*16;
  #pragma unroll
  for (int j=0;j<8;j++) Bsh[threadIdx.x + 256*j] = src[threadIdx.x + 256*j];
  __syncthreads();

  float dta[8], uva[8], zva[8], dtb[8], uvb[8], zvb[8];
  #pragma unroll
  for (int j=0;j<8;j++){
    size_t r = (size_t)(row0+j);
    dta[j] = h2f(delta16[r*D_INNER+c]);
    uva[j] = b2f(uu[r*D_INNER+c]);
    zva[j] = b2f(xz[r*4096 + D_INNER + c]);
  }
  #pragma unroll 1
  for (int g=0; g<CHUNK; g+=16){
    #pragma unroll
    for (int j=0;j<8;j++){
      int tl = g+8+j; tl = tl < CHUNK ? tl : CHUNK-1;
      size_t r = (size_t)(row0+tl);
      dtb[j] = h2f(delta16[r*D_INNER+c]);
      uvb[j] = b2f(uu[r*D_INNER+c]);
      zvb[j] = b2f(xz[r*4096 + D_INNER + c]);
    }
    #pragma unroll
    for (int j=0;j<8;j++){
      float dt=dta[j], uv=uva[j], zv=zva[j];
      float xv=dt*uv, y=0.f;
      const float* Bt = &Bsh[(g+j)*16];
      #pragma unroll
      for (int s=0;s<16;s++){
        h[s] = fmaf(h[s], __expf(dt*A[s]), xv*Bt[s]);
        y += h[s];
      }
      y = fmaf(uv, Dc, y);
      float gz = zv/(1.f+__expf(-zv));
      yg[(size_t)(row0+g+j)*D_INNER + c] = f2b(y*gz);
    }
    #pragma unroll
    for (int j=0;j<8;j++){
      int tl = g+16+j; tl = tl < CHUNK ? tl : CHUNK-1;
      size_t r = (size_t)(row0+tl);
      dta[j] = h2f(delta16[r*D_INNER+c]);
      uva[j] = b2f(uu[r*D_INNER+c]);
      zva[j] = b2f(xz[r*4096 + D_INNER + c]);
    }
    #pragma unroll
    for (int j=0;j<8;j++){
      float dt=dtb[j], uv=uvb[j], zv=zvb[j];
      float xv=dt*uv, y=0.f;
      const float* Bt = &Bsh[(g+8+j)*16];
      #pragma unroll
      for (int s=0;s<16;s++){
        h[s] = fmaf(h[s], __expf(dt*A[s]), xv*Bt[s]);
        y += h[s];
      }
      y = fmaf(uv, Dc, y);
      float gz = zv/(1.f+__expf(-zv));
      yg[(size_t)(row0+g+8+j)*D_INNER + c] = f2b(y*gz);
    }
  }
}

// ---------------------------------------------------------------------------
extern "C" void kernel_launch(void* const* d_in, const int* in_sizes, int n_in,
                              void* d_out, int out_size, void* d_ws, size_t ws_size,
                              hipStream_t stream)
{
  const float* x    = (const float*)d_in[0];
  const float* lng  = (const float*)d_in[1];
  const float* lnb  = (const float*)d_in[2];
  const float* W1   = (const float*)d_in[3];
  const float* cw   = (const float*)d_in[4];
  const float* cb   = (const float*)d_in[5];
  const float* Wx   = (const float*)d_in[6];
  const float* Wdt  = (const float*)d_in[7];
  const float* dtb  = (const float*)d_in[8];
  const float* Alog = (const float*)d_in[9];
  const float* Dpar = (const float*)d_in[10];
  const float* Wout = (const float*)d_in[11];

  // workspace layout (MiB offsets), total ~199 MiB:
  //  [0,32)      delta fp16 8192x2048   ([0,16) doubles as xn bf16, dead pre-gemm1)
  //  [32,96)     xz bf16 8192x4096
  //  [96,128)    uu bf16 8192x2048
  //  [128,128.5) Bm fp32 8192x16
  //  [129,137)   W1t bf16 [4096][1024] ; [137,145) Wdtt bf16 [2048][2048] ;
  //  [145,149)   Woutt bf16 [1024][2048]
  //  [149,181)   yg bf16 8192x2048
  //  [181,189)   hend fp32 ; [189,189.5) sumdt fp32 ; [190,198) hin fp32
  //  [198,198.1) Wxt bf16 [16][2048]
  char* ws = (char*)d_ws;
  u16*   dlt   = (u16*)(ws);
  u16*   xn    = (u16*)(ws);                 // alias (sequenced)
  u16*   xz    = (u16*)(ws + (32llu<<20));
  u16*   uu    = (u16*)(ws + (96llu<<20));
  float* Bm    = (float*)(ws + (128llu<<20));
  u16*   W1t   = (u16*)(ws + (129llu<<20));
  u16*   Wdtt  = (u16*)(ws + (137llu<<20));
  u16*   Woutt = (u16*)(ws + (145llu<<20));
  u16*   yg    = (u16*)(ws + (149llu<<20));
  float* hend  = (float*)(ws + (181llu<<20));
  float* sumdt = (float*)(ws + (189llu<<20));
  float* hin   = (float*)(ws + (190llu<<20));
  u16*   Wxt   = (u16*)(ws + (198llu<<20));

  // weights -> bf16, transposed to [N][K]
  wcvt_t_kernel<<<dim3(2*D_INNER/32, D_MODEL/32), 256, 0, stream>>>(W1,  W1t,  D_MODEL, 2*D_INNER);
  wcvt_t_kernel<<<dim3(D_INNER/32,  D_INNER/32), 256, 0, stream>>>(Wdt, Wdtt, D_INNER, D_INNER);
  wcvt_t_kernel<<<dim3(D_MODEL/32,  D_INNER/32), 256, 0, stream>>>(Wout,Woutt,D_INNER, D_MODEL);
  wxcvt_kernel<<<D_INNER/256, 256, 0, stream>>>(Wx, Wxt);

  ln_kernel<<<NROWS, 256, 0, stream>>>(x, lng, lnb, xn);

  gemm_direct<0><<<dim3(2*D_INNER/128, NROWS/128), 256, 0, stream>>>(
      xn, W1t, nullptr, nullptr, (void*)xz, NROWS, 2*D_INNER, D_MODEL);

  conv_silu_kernel<<<(NROWS*D_INNER)/256, 256, 0, stream>>>(xz, cw, cb, uu);

  xproj_kernel<<<NROWS/4, 256, 0, stream>>>(uu, Wxt, Bm);

  gemm_direct<1><<<dim3(D_INNER/128, NROWS/128), 256, 0, stream>>>(
      uu, Wdtt, dtb, nullptr, (void*)dlt, NROWS, D_INNER, D_INNER);

  scan_partial<<<dim3(D_INNER/256, BATCH, NCHUNK), 256, 0, stream>>>(
      uu, dlt, Bm, Alog, hend, sumdt);
  scan_combine<<<dim3(D_INNER/256, BATCH), 256, 0, stream>>>(
      hend, sumdt, Alog, hin);
  scan_final<<<dim3(D_INNER/256, BATCH, NCHUNK), 256, 0, stream>>>(
      uu, dlt, Bm, xz, Alog, Dpar, hin, yg);

  gemm_direct<2><<<dim3(D_MODEL/128, NROWS/128), 256, 0, stream>>>(
      yg, Woutt, nullptr, x, d_out, NROWS, D_MODEL, D_INNER);

  (void)in_sizes; (void)n_in; (void)out_size; (void)ws_size;
}

// Round 8
// 759.484 us; speedup vs baseline: 1.3934x; 1.3934x over previous
//
#include <hip/hip_runtime.h>

typedef unsigned short u16;
typedef unsigned int   u32;

#define D_MODEL 1024
#define D_INNER 2048
#define D_STATE 16
#define SEQLEN  2048
#define BATCH   4
#define NROWS   (BATCH*SEQLEN)   // 8192
#define CHUNK   128
#define NCHUNK  (SEQLEN/CHUNK)   // 16

__device__ __forceinline__ float b2f(u16 v){
  union { u32 i; float f; } u; u.i = ((u32)v) << 16; return u.f;
}
__device__ __forceinline__ u16 f2b(float f){
  union { float f; u32 i; } u; u.f = f;
  u32 x = u.i;
  return (u16)((x + 0x7fffu + ((x >> 16) & 1u)) >> 16);  // RNE
}
__device__ __forceinline__ float h2f(u16 v){
  _Float16 h; __builtin_memcpy(&h, &v, 2); return (float)h;
}
__device__ __forceinline__ u16 f2h(float f){
  _Float16 h = (_Float16)f; u16 v; __builtin_memcpy(&v, &h, 2); return v;
}

typedef __bf16 bf16x8 __attribute__((ext_vector_type(8)));
typedef float  f32x4  __attribute__((ext_vector_type(4)));

// async global->LDS, 16B per lane; data for lane i lands at lds + i*16B.
__device__ __forceinline__ void async16(u16* lds, const u16* g){
  __builtin_amdgcn_global_load_lds(
      (const __attribute__((address_space(1))) void*)g,
      (__attribute__((address_space(3))) void*)lds,
      16, 0, 0);
}

// ---------------------------------------------------------------------------
// fp32 [Kd][Nd] -> bf16 transposed [Nd][Kd]   (32x32 LDS tiles)
// ---------------------------------------------------------------------------
__global__ __launch_bounds__(256) void wcvt_t_kernel(
    const float* __restrict__ W, u16* __restrict__ Bt, int Kd, int Nd)
{
  __shared__ u16 tile[32][33];
  const int n0 = blockIdx.x*32, k0 = blockIdx.y*32;
  const int tx = threadIdx.x & 31, ty = threadIdx.x >> 5;  // ty 0..7
  #pragma unroll
  for (int i=0;i<32;i+=8)
    tile[ty+i][tx] = f2b(W[(size_t)(k0+ty+i)*Nd + n0+tx]);   // tile[k][n]
  __syncthreads();
  #pragma unroll
  for (int i=0;i<32;i+=8)
    Bt[(size_t)(n0+ty+i)*Kd + k0+tx] = tile[tx][ty+i];
}

// Wx [2048][32] cols 16..31 -> Wxt bf16 [16][2048]
__global__ __launch_bounds__(256) void wxcvt_kernel(
    const float* __restrict__ Wx, u16* __restrict__ Wxt)
{
  const int k = blockIdx.x*256 + threadIdx.x;   // 0..2047
  #pragma unroll
  for (int n=0;n<16;n++)
    Wxt[n*D_INNER + k] = f2b(Wx[(size_t)k*32 + 16 + n]);
}

// ---------------------------------------------------------------------------
// Fused LayerNorm: x[row][1024] fp32 -> xn bf16
// ---------------------------------------------------------------------------
__global__ __launch_bounds__(256) void ln_kernel(
    const float* __restrict__ x, const float* __restrict__ g,
    const float* __restrict__ be, u16* __restrict__ xn)
{
  const int row = blockIdx.x;
  const float* xr = x + (size_t)row * D_MODEL;
  const int tid = threadIdx.x;
  float v[4]; float s = 0.f, s2 = 0.f;
  #pragma unroll
  for (int j=0;j<4;j++){
    float f = xr[tid + 256*j];
    v[j] = f; s += f; s2 += f*f;
  }
  #pragma unroll
  for (int o=32;o>0;o>>=1){ s += __shfl_down(s,o); s2 += __shfl_down(s2,o); }
  __shared__ float sh[8];
  const int wave = tid>>6, lane = tid&63;
  if (lane==0){ sh[wave]=s; sh[4+wave]=s2; }
  __syncthreads();
  const float ts  = sh[0]+sh[1]+sh[2]+sh[3];
  const float ts2 = sh[4]+sh[5]+sh[6]+sh[7];
  const float mu  = ts * (1.f/D_MODEL);
  const float var = ts2 * (1.f/D_MODEL) - mu*mu;
  const float rstd = rsqrtf(var + 1e-5f);
  u16* xo = xn + (size_t)row * D_MODEL;
  #pragma unroll
  for (int j=0;j<4;j++){
    int i = tid + 256*j;
    xo[i] = f2b((v[j]-mu)*rstd * g[i] + be[i]);
  }
}

// ---------------------------------------------------------------------------
// 128x128 MFMA GEMM, BK=64 (two 128x32 K-tiles per barrier), global_load_lds
// staging, XOR-swizzled 16B granules (verified 0-conflict in r6), XCD-aware
// block swizzle: xcd=id&7 owns gx/8 n-columns, walks m within a column so the
// current 512KB B-column stays L2-resident per XCD.
// A [M][K] bf16 ; Bt [N][K] bf16 (pre-transposed). 4 waves, 64x64 per wave.
// EPI 0: bf16 ; EPI 1: softplus(v+bias)->fp16 ; EPI 2: v+resid->fp32
// ---------------------------------------------------------------------------
template<int EPI>
__global__ __launch_bounds__(256) void gemm_bk64(
    const u16* __restrict__ A, const u16* __restrict__ Bt,
    const float* __restrict__ bias, const float* __restrict__ resid,
    void* __restrict__ outv, int M, int N, int K, int gx, int gy)
{
  __shared__ __align__(16) u16 As[2*128*32];   // 16 KB: ks0 tile, ks1 tile
  __shared__ __align__(16) u16 Bs[2*128*32];
  const int tid  = threadIdx.x;
  const int wave = tid >> 6, lane = tid & 63;
  const int quad = lane >> 4, l16 = lane & 15;

  // XCD swizzle: consecutive blocks on one XCD share the same n-column.
  const int lid = blockIdx.x;
  const int xcd = lid & 7, q = lid >> 3;
  const int cpx = gx >> 3;
  const int qd  = q / gy;
  const int bx  = xcd*cpx + qd;
  const int by  = q - qd*gy;
  const int m0 = by*128, n0 = bx*128;
  const int wm = (wave & 1)*64, wn = (wave >> 1)*64;

  // staging: wave covers rows wave*32..+31 of both tiles
  const int srow = wave*32 + (lane >> 2);
  const int gcol = ((lane & 3) ^ ((lane >> 3) & 3)) * 8;  // swizzled granule
  const u16* pA = A  + (size_t)(m0 + srow)*K + gcol;
  const u16* pB = Bt + (size_t)(n0 + srow)*K + gcol;
  u16* lA = &As[(wave*32)*32];
  u16* lB = &Bs[(wave*32)*32];

  // fragment LDS byte offsets within a ks tile
  const int sw   = quad ^ ((l16 >> 1) & 3);
  const int aoff = (wm + l16)*64 + sw*16;   // + mf*1024 + ks*8192
  const int boff = (wn + l16)*64 + sw*16;   // + nf*1024 + ks*8192

  f32x4 acc[4][4];
  #pragma unroll
  for (int i=0;i<4;i++)
    #pragma unroll
    for (int j=0;j<4;j++) acc[i][j] = (f32x4){0.f,0.f,0.f,0.f};

  for (int k0 = 0; k0 < K; k0 += 64) {
    __syncthreads();                       // prev fragments consumed
    async16(lA,               pA + k0);                       // ks0
    async16(lA + 16*32,       pA + (size_t)16*K + k0);
    async16(lA + 4096,        pA + k0 + 32);                  // ks1
    async16(lA + 4096+16*32,  pA + (size_t)16*K + k0 + 32);
    async16(lB,               pB + k0);
    async16(lB + 16*32,       pB + (size_t)16*K + k0);
    async16(lB + 4096,        pB + k0 + 32);
    async16(lB + 4096+16*32,  pB + (size_t)16*K + k0 + 32);
    __syncthreads();                       // staging drained

    #pragma unroll
    for (int ks=0; ks<2; ks++){
      bf16x8 afr[4], bfr[4];
      #pragma unroll
      for (int mf=0; mf<4; mf++)
        afr[mf] = *reinterpret_cast<const bf16x8*>((const char*)As + ks*8192 + aoff + mf*1024);
      #pragma unroll
      for (int nf=0; nf<4; nf++)
        bfr[nf] = *reinterpret_cast<const bf16x8*>((const char*)Bs + ks*8192 + boff + nf*1024);
      #pragma unroll
      for (int mf=0; mf<4; mf++)
        #pragma unroll
        for (int nf=0; nf<4; nf++)
          acc[mf][nf] = __builtin_amdgcn_mfma_f32_16x16x32_bf16(afr[mf], bfr[nf], acc[mf][nf], 0, 0, 0);
    }
  }

  #pragma unroll
  for (int mf=0; mf<4; mf++){
    #pragma unroll
    for (int nf=0; nf<4; nf++){
      const int col = n0 + wn + nf*16 + l16;
      #pragma unroll
      for (int j=0;j<4;j++){
        const int row = m0 + wm + mf*16 + quad*4 + j;
        float v = acc[mf][nf][j];
        if (EPI == 1) {
          v += bias[col];
          v = (v > 20.f) ? v : log1pf(__expf(v));
          ((u16*)outv)[(size_t)row*N + col] = f2h(v);       // delta fp16
        } else if (EPI == 2) {
          v += resid[(size_t)row*N + col];
          ((float*)outv)[(size_t)row*N + col] = v;          // final out fp32
        } else {
          ((u16*)outv)[(size_t)row*N + col] = f2b(v);       // bf16 activation
        }
      }
    }
  }
}

// ---------------------------------------------------------------------------
// Causal depthwise conv(width 4) + bias + SiLU, 8 channels/thread vectorized.
// ---------------------------------------------------------------------------
__global__ __launch_bounds__(256) void conv_silu_kernel(
    const u16* __restrict__ xz, const float* __restrict__ cw,
    const float* __restrict__ cb, u16* __restrict__ u)
{
  const int idx = blockIdx.x*256 + threadIdx.x;   // (bt, c-group)
  const int c0 = (idx & 255) * 8;
  const int bt = idx >> 8;
  const int t  = bt & (SEQLEN-1);
  float acc[8];
  #pragma unroll
  for (int j=0;j<8;j++) acc[j] = cb[c0+j];
  #pragma unroll
  for (int k=0;k<4;k++){
    if (t - 3 + k >= 0){
      bf16x8 xv = *reinterpret_cast<const bf16x8*>(xz + (size_t)(bt-3+k)*4096 + c0);
      #pragma unroll
      for (int j=0;j<8;j++)
        acc[j] = fmaf(cw[(c0+j)*4 + k], (float)xv[j], acc[j]);
    }
  }
  u16 o[8];
  #pragma unroll
  for (int j=0;j<8;j++){
    float sv = acc[j] / (1.f + __expf(-acc[j]));
    o[j] = f2b(sv);
  }
  __builtin_memcpy(u + (size_t)bt*D_INNER + c0, o, 16);
}

// ---------------------------------------------------------------------------
// x_proj (cols 16..31 only): one wave per row, lane=(kq,n), bf16x8 both streams.
// ---------------------------------------------------------------------------
__global__ __launch_bounds__(256) void xproj_kernel(
    const u16* __restrict__ u, const u16* __restrict__ Wxt, float* __restrict__ Bm)
{
  const int wave = threadIdx.x >> 6, lane = threadIdx.x & 63;
  const int m = blockIdx.x*4 + wave;
  const int n = lane & 15, kq = lane >> 4;
  const u16* ur = u   + (size_t)m*D_INNER + kq*512;
  const u16* wr = Wxt + (size_t)n*D_INNER + kq*512;
  float acc = 0.f;
  #pragma unroll 4
  for (int i=0;i<512;i+=8){
    bf16x8 uv = *reinterpret_cast<const bf16x8*>(ur + i);
    bf16x8 wv = *reinterpret_cast<const bf16x8*>(wr + i);
    #pragma unroll
    for (int j=0;j<8;j++) acc = fmaf((float)uv[j], (float)wv[j], acc);
  }
  acc += __shfl_xor(acc, 16);
  acc += __shfl_xor(acc, 32);
  if (lane < 16) Bm[(size_t)m*16 + n] = acc;
}

// ---------------------------------------------------------------------------
// Chunked selective scan, 3 passes (exact linear-recurrence decomposition).
// ---------------------------------------------------------------------------
__global__ __launch_bounds__(256) void scan_partial(
    const u16* __restrict__ uu, const u16* __restrict__ delta16,
    const float* __restrict__ Bm, const float* __restrict__ Alog,
    float* __restrict__ hend, float* __restrict__ sumdt)
{
  const int b = blockIdx.y, ch = blockIdx.z;
  const int c = blockIdx.x*256 + threadIdx.x;
  const int row0 = b*SEQLEN + ch*CHUNK;
  float A[16], h[16];
  #pragma unroll
  for (int s=0;s<16;s++){ A[s] = -__expf(Alog[c*16+s]); h[s]=0.f; }
  __shared__ float Bsh[CHUNK*16];
  const float* src = Bm + (size_t)row0*16;
  #pragma unroll
  for (int j=0;j<8;j++) Bsh[threadIdx.x + 256*j] = src[threadIdx.x + 256*j];
  __syncthreads();

  float S = 0.f;
  float dta[8], uva[8], dtb[8], uvb[8];
  #pragma unroll
  for (int j=0;j<8;j++){
    size_t r = (size_t)(row0+j);
    dta[j] = h2f(delta16[r*D_INNER+c]);
    uva[j] = b2f(uu[r*D_INNER+c]);
  }
  #pragma unroll 1
  for (int g=0; g<CHUNK; g+=16){
    #pragma unroll
    for (int j=0;j<8;j++){
      int tl = g+8+j; tl = tl < CHUNK ? tl : CHUNK-1;
      size_t r = (size_t)(row0+tl);
      dtb[j] = h2f(delta16[r*D_INNER+c]);
      uvb[j] = b2f(uu[r*D_INNER+c]);
    }
    #pragma unroll
    for (int j=0;j<8;j++){
      float dt=dta[j], uv=uva[j]; S += dt; float xv=dt*uv;
      const float* Bt = &Bsh[(g+j)*16];
      #pragma unroll
      for (int s=0;s<16;s++) h[s] = fmaf(h[s], __expf(dt*A[s]), xv*Bt[s]);
    }
    #pragma unroll
    for (int j=0;j<8;j++){
      int tl = g+16+j; tl = tl < CHUNK ? tl : CHUNK-1;
      size_t r = (size_t)(row0+tl);
      dta[j] = h2f(delta16[r*D_INNER+c]);
      uva[j] = b2f(uu[r*D_INNER+c]);
    }
    #pragma unroll
    for (int j=0;j<8;j++){
      float dt=dtb[j], uv=uvb[j]; S += dt; float xv=dt*uv;
      const float* Bt = &Bsh[(g+8+j)*16];
      #pragma unroll
      for (int s=0;s<16;s++) h[s] = fmaf(h[s], __expf(dt*A[s]), xv*Bt[s]);
    }
  }
  const size_t base = ((size_t)(b*NCHUNK+ch)*16)*D_INNER + c;
  #pragma unroll
  for (int s=0;s<16;s++) hend[base + (size_t)s*D_INNER] = h[s];
  sumdt[(size_t)(b*NCHUNK+ch)*D_INNER + c] = S;
}

__global__ __launch_bounds__(256) void scan_combine(
    const float* __restrict__ hend, const float* __restrict__ sumdt,
    const float* __restrict__ Alog, float* __restrict__ hin)
{
  const int b = blockIdx.y;
  const int c = blockIdx.x*256 + threadIdx.x;
  float A[16], h[16];
  #pragma unroll
  for (int s=0;s<16;s++){ A[s] = -__expf(Alog[c*16+s]); h[s]=0.f; }
  #pragma unroll 1
  for (int k=0;k<NCHUNK;k++){
    const size_t base = ((size_t)(b*NCHUNK+k)*16)*D_INNER + c;
    #pragma unroll
    for (int s=0;s<16;s++) hin[base + (size_t)s*D_INNER] = h[s];
    const float S = sumdt[(size_t)(b*NCHUNK+k)*D_INNER + c];
    #pragma unroll
    for (int s=0;s<16;s++)
      h[s] = fmaf(h[s], __expf(S*A[s]), hend[base + (size_t)s*D_INNER]);
  }
}

__global__ __launch_bounds__(256) void scan_final(
    const u16* __restrict__ uu, const u16* __restrict__ delta16,
    const float* __restrict__ Bm, const u16* __restrict__ xz,
    const float* __restrict__ Alog, const float* __restrict__ Dpar,
    const float* __restrict__ hin, u16* __restrict__ yg)
{
  const int b = blockIdx.y, ch = blockIdx.z;
  const int c = blockIdx.x*256 + threadIdx.x;
  const int row0 = b*SEQLEN + ch*CHUNK;
  float A[16], h[16];
  const size_t base = ((size_t)(b*NCHUNK+ch)*16)*D_INNER + c;
  #pragma unroll
  for (int s=0;s<16;s++){
    A[s] = -__expf(Alog[c*16+s]);
    h[s] = hin[base + (size_t)s*D_INNER];
  }
  const float Dc = Dpar[c];
  __shared__ float Bsh[CHUNK*16];
  const float* src = Bm + (size_t)row0*16;
  #pragma unroll
  for (int j=0;j<8;j++) Bsh[threadIdx.x + 256*j] = src[threadIdx.x + 256*j];
  __syncthreads();

  float dta[8], uva[8], zva[8], dtb[8], uvb[8], zvb[8];
  #pragma unroll
  for (int j=0;j<8;j++){
    size_t r = (size_t)(row0+j);
    dta[j] = h2f(delta16[r*D_INNER+c]);
    uva[j] = b2f(uu[r*D_INNER+c]);
    zva[j] = b2f(xz[r*4096 + D_INNER + c]);
  }
  #pragma unroll 1
  for (int g=0; g<CHUNK; g+=16){
    #pragma unroll
    for (int j=0;j<8;j++){
      int tl = g+8+j; tl = tl < CHUNK ? tl : CHUNK-1;
      size_t r = (size_t)(row0+tl);
      dtb[j] = h2f(delta16[r*D_INNER+c]);
      uvb[j] = b2f(uu[r*D_INNER+c]);
      zvb[j] = b2f(xz[r*4096 + D_INNER + c]);
    }
    #pragma unroll
    for (int j=0;j<8;j++){
      float dt=dta[j], uv=uva[j], zv=zva[j];
      float xv=dt*uv, y=0.f;
      const float* Bt = &Bsh[(g+j)*16];
      #pragma unroll
      for (int s=0;s<16;s++){
        h[s] = fmaf(h[s], __expf(dt*A[s]), xv*Bt[s]);
        y += h[s];
      }
      y = fmaf(uv, Dc, y);
      float gz = zv/(1.f+__expf(-zv));
      yg[(size_t)(row0+g+j)*D_INNER + c] = f2b(y*gz);
    }
    #pragma unroll
    for (int j=0;j<8;j++){
      int tl = g+16+j; tl = tl < CHUNK ? tl : CHUNK-1;
      size_t r = (size_t)(row0+tl);
      dta[j] = h2f(delta16[r*D_INNER+c]);
      uva[j] = b2f(uu[r*D_INNER+c]);
      zva[j] = b2f(xz[r*4096 + D_INNER + c]);
    }
    #pragma unroll
    for (int j=0;j<8;j++){
      float dt=dtb[j], uv=uvb[j], zv=zvb[j];
      float xv=dt*uv, y=0.f;
      const float* Bt = &Bsh[(g+8+j)*16];
      #pragma unroll
      for (int s=0;s<16;s++){
        h[s] = fmaf(h[s], __expf(dt*A[s]), xv*Bt[s]);
        y += h[s];
      }
      y = fmaf(uv, Dc, y);
      float gz = zv/(1.f+__expf(-zv));
      yg[(size_t)(row0+g+8+j)*D_INNER + c] = f2b(y*gz);
    }
  }
}

// ---------------------------------------------------------------------------
extern "C" void kernel_launch(void* const* d_in, const int* in_sizes, int n_in,
                              void* d_out, int out_size, void* d_ws, size_t ws_size,
                              hipStream_t stream)
{
  const float* x    = (const float*)d_in[0];
  const float* lng  = (const float*)d_in[1];
  const float* lnb  = (const float*)d_in[2];
  const float* W1   = (const float*)d_in[3];
  const float* cw   = (const float*)d_in[4];
  const float* cb   = (const float*)d_in[5];
  const float* Wx   = (const float*)d_in[6];
  const float* Wdt  = (const float*)d_in[7];
  const float* dtb  = (const float*)d_in[8];
  const float* Alog = (const float*)d_in[9];
  const float* Dpar = (const float*)d_in[10];
  const float* Wout = (const float*)d_in[11];

  // workspace layout (MiB offsets), total ~199 MiB (same as r7)
  char* ws = (char*)d_ws;
  u16*   dlt   = (u16*)(ws);
  u16*   xn    = (u16*)(ws);                 // alias (sequenced)
  u16*   xz    = (u16*)(ws + (32llu<<20));
  u16*   uu    = (u16*)(ws + (96llu<<20));
  float* Bm    = (float*)(ws + (128llu<<20));
  u16*   W1t   = (u16*)(ws + (129llu<<20));
  u16*   Wdtt  = (u16*)(ws + (137llu<<20));
  u16*   Woutt = (u16*)(ws + (145llu<<20));
  u16*   yg    = (u16*)(ws + (149llu<<20));
  float* hend  = (float*)(ws + (181llu<<20));
  float* sumdt = (float*)(ws + (189llu<<20));
  float* hin   = (float*)(ws + (190llu<<20));
  u16*   Wxt   = (u16*)(ws + (198llu<<20));

  // weights -> bf16, transposed to [N][K]
  wcvt_t_kernel<<<dim3(2*D_INNER/32, D_MODEL/32), 256, 0, stream>>>(W1,  W1t,  D_MODEL, 2*D_INNER);
  wcvt_t_kernel<<<dim3(D_INNER/32,  D_INNER/32), 256, 0, stream>>>(Wdt, Wdtt, D_INNER, D_INNER);
  wcvt_t_kernel<<<dim3(D_MODEL/32,  D_INNER/32), 256, 0, stream>>>(Wout,Woutt,D_INNER, D_MODEL);
  wxcvt_kernel<<<D_INNER/256, 256, 0, stream>>>(Wx, Wxt);

  ln_kernel<<<NROWS, 256, 0, stream>>>(x, lng, lnb, xn);

  {
    const int gx = 2*D_INNER/128, gy = NROWS/128;   // 32 x 64
    gemm_bk64<0><<<gx*gy, 256, 0, stream>>>(
        xn, W1t, nullptr, nullptr, (void*)xz, NROWS, 2*D_INNER, D_MODEL, gx, gy);
  }

  conv_silu_kernel<<<(NROWS*D_INNER/8)/256, 256, 0, stream>>>(xz, cw, cb, uu);

  xproj_kernel<<<NROWS/4, 256, 0, stream>>>(uu, Wxt, Bm);

  {
    const int gx = D_INNER/128, gy = NROWS/128;     // 16 x 64
    gemm_bk64<1><<<gx*gy, 256, 0, stream>>>(
        uu, Wdtt, dtb, nullptr, (void*)dlt, NROWS, D_INNER, D_INNER, gx, gy);
  }

  scan_partial<<<dim3(D_INNER/256, BATCH, NCHUNK), 256, 0, stream>>>(
      uu, dlt, Bm, Alog, hend, sumdt);
  scan_combine<<<dim3(D_INNER/256, BATCH), 256, 0, stream>>>(
      hend, sumdt, Alog, hin);
  scan_final<<<dim3(D_INNER/256, BATCH, NCHUNK), 256, 0, stream>>>(
      uu, dlt, Bm, xz, Alog, Dpar, hin, yg);

  {
    const int gx = D_MODEL/128, gy = NROWS/128;     // 8 x 64
    gemm_bk64<2><<<gx*gy, 256, 0, stream>>>(
        yg, Woutt, nullptr, x, d_out, NROWS, D_MODEL, D_INNER, gx, gy);
  }

  (void)in_sizes; (void)n_in; (void)out_size; (void)ws_size;
}